// Round 5
// baseline (367.342 us; speedup 1.0000x reference)
//
#include <hip/hip_runtime.h>

#define NN 100000
#define NE 600000
#define ET (NE + NN)
#define D 128
#define NREL 16
#define NDS 64                   // dst slices
#define DSL 1563                 // ceil(NN/NDS); 64*1563 = 100032 >= NN
#define NBIN (NREL * NDS + NDS)  // 1088: rel-major edge bins + 64 self bins
#define SELF0 (NREL * NDS)       // 1024
#define SCANB 391                // 391*256 = 100096 >= NN
#define TPB 4                    // tiles per gemm block
#define MAXTILES 12544           // >= 600000/64 + 1024 + 1600 = 11999
#define GEMMG ((MAXTILES + TPB - 1) / TPB)
#define TINFOG ((MAXTILES + 255) / 256)
#define WGRID 1088  // 17*16384/256

typedef short short8 __attribute__((ext_vector_type(8)));
typedef float f32x4 __attribute__((ext_vector_type(4)));
typedef unsigned int u32x4 __attribute__((ext_vector_type(4)));

// meta layout (ints); bins rel-major: bin = rel*64 + dslice; self = 1024 + dslice
#define C0 0                     // counts[NBIN]
#define O0 1088                  // offsets[NBIN+1]
#define CU0 2177                 // cursors[NBIN]
#define T0 3265                  // tileoff[NBIN+1]   (total 4354 ints)

// ws layout (bytes)
#define WT_OFF   0                 // 17*128*128 bf16 = 557056
#define META_OFF 557056            // 17536 (4354 ints used)
#define DH_OFF   574592            // dstHist: 100000 ints (dead after k_scan1)
#define TI_OFF   574592            // tileInfo int4[MAXTILES] ALIASES dstHist (200704 B)
#define DO_OFF   974592            // dstOff: 100001 ints (+pad)
#define DC_OFF   1374600           // dstCursor: 100000 ints
#define BS_OFF   1774600           // blockSums: 391 ints (+pad -> SCP 8-aligned)
#define SCP_OFF  1776176           // sCP: 700064 int2
#define XB_OFF   7376688           // xb: 100000*128 bf16  (mode B)
#define SR_OFF   7376688           // sRow ALIASES xb (mode !A only; no xb/msg then)
#define MSGA_OFF 7376688           // msg ALIASES xb (mode A&&!B: no xb then)
#define MSGB_OFF 32976688          // msg (mode B)
#define NEED_B   (MSGB_OFF + (size_t)ET * 128 * 2)
#define NEED_A   (MSGA_OFF + (size_t)ET * 128 * 2)

__device__ __forceinline__ unsigned short f2bf(float f) {
  unsigned u = __builtin_bit_cast(unsigned, f);
  u += 0x7fffu + ((u >> 16) & 1u);   // RNE; inputs finite/normal
  return (unsigned short)(u >> 16);
}

// LDS-only barrier: no vmcnt drain (prefetch regs / nt stores stay in flight).
__device__ __forceinline__ void lds_barrier() {
  asm volatile("s_waitcnt lgkmcnt(0)" ::: "memory");
  __builtin_amdgcn_s_barrier();
}

// blockIdx < WGRID: wT[r][o][i] = sum_b coef[r,b]*bases[b][i][o]; slot16 = w_self.
// else: x fp32 -> xb bf16 (4 elems/thread).
__global__ __launch_bounds__(256) void k_prep(const float* __restrict__ bases,
    const float* __restrict__ coef, const float* __restrict__ w_self,
    unsigned short* __restrict__ wT, const float* __restrict__ x,
    unsigned short* __restrict__ xb)
{
  if (blockIdx.x < WGRID) {
    int idx = blockIdx.x * 256 + threadIdx.x;   // < 17*16384
    int r = idx >> 14;
    int t = idx & 16383;
    float v;
    if (r < 16) {
      int o = t >> 7, i = t & 127;
      float acc = 0.f;
      #pragma unroll
      for (int b = 0; b < 8; ++b)
        acc += coef[r * 8 + b] * bases[b * 16384 + i * 128 + o];
      v = acc;
    } else {
      v = w_self[t];
    }
    wT[idx] = f2bf(v);
  } else {
    int i = (blockIdx.x - WGRID) * 256 + threadIdx.x;
    if (i >= NN * D / 4) return;
    f32x4 f = __builtin_nontemporal_load((const f32x4*)(x + (size_t)i * 4));
    unsigned short s0 = f2bf(f[0]), s1 = f2bf(f[1]), s2 = f2bf(f[2]), s3 = f2bf(f[3]);
    unsigned long long pk = (unsigned long long)s0 | ((unsigned long long)s1 << 16)
                          | ((unsigned long long)s2 << 32) | ((unsigned long long)s3 << 48);
    *(unsigned long long*)(xb + (size_t)i * 4) = pk;
  }
}

// (rel,dslice) histogram (LDS) + dst histogram (global atomics)
__global__ __launch_bounds__(256) void k_hist(const int* __restrict__ ei,
    const int* __restrict__ et, int* __restrict__ meta, int* __restrict__ dstHist)
{
  __shared__ int h[NBIN];
  int tid = threadIdx.x;
  for (int i = tid; i < NBIN; i += 256) h[i] = 0;
  __syncthreads();
  for (int e = blockIdx.x * 256 + tid; e < NE; e += gridDim.x * 256) {
    int dst = ei[e];
    atomicAdd(&h[et[e] * NDS + dst / DSL], 1);
    atomicAdd(&dstHist[dst], 1);
  }
  __syncthreads();
  for (int i = tid; i < NBIN; i += 256)
    if (h[i]) atomicAdd(&meta[C0 + i], h[i]);
}

__global__ __launch_bounds__(256) void k_scan1(const int* __restrict__ dstHist,
    int* __restrict__ dstOff, int* __restrict__ blockSums)
{
  __shared__ int sh[256];
  int tid = threadIdx.x;
  int d = blockIdx.x * 256 + tid;
  int v = (d < NN) ? (dstHist[d] + 1) : 0;   // +1: virtual self edge
  sh[tid] = v;
  __syncthreads();
  #pragma unroll
  for (int ofs = 1; ofs < 256; ofs <<= 1) {
    int t = (tid >= ofs) ? sh[tid - ofs] : 0;
    __syncthreads();
    sh[tid] += t;
    __syncthreads();
  }
  if (d < NN) dstOff[d] = sh[tid] - v;
  if (tid == 255) blockSums[blockIdx.x] = sh[tid];
}

__global__ __launch_bounds__(512) void k_scan2(int* __restrict__ blockSums, int* __restrict__ meta)
{
  __shared__ int sh[SCANB];
  int tid = threadIdx.x;
  if (tid < SCANB) sh[tid] = blockSums[tid];
  __syncthreads();
  if (tid == 0) {
    int run = 0;
    for (int i = 0; i < SCANB; ++i) { int c = sh[i]; sh[i] = run; run += c; }
    for (int s = 0; s < NDS; ++s)
      meta[C0 + SELF0 + s] = min(DSL, NN - s * DSL);
    int off = 0, toff = 0;
    for (int bn = 0; bn < NBIN; ++bn) {
      meta[O0 + bn] = off;
      meta[CU0 + bn] = off;
      meta[T0 + bn] = toff;
      int c = meta[C0 + bn];
      off += c;
      toff += (c + 63) >> 6;
    }
    meta[O0 + NBIN] = off;
    meta[T0 + NBIN] = toff;
  }
  __syncthreads();
  if (tid < SCANB) blockSums[tid] = sh[tid];
}

__global__ __launch_bounds__(256) void k_scan3(int* __restrict__ dstOff,
    const int* __restrict__ blockSums, int* __restrict__ dstCursor,
    int2* __restrict__ sCP, const int* __restrict__ meta)
{
  int tid = threadIdx.x;
  int d = blockIdx.x * 256 + tid;
  int base = blockSums[blockIdx.x];
  if (d < NN) {
    int o = dstOff[d] + base;
    dstOff[d] = o;
    dstCursor[d] = o + 1;
    int s = d / DSL;
    int pos = meta[O0 + SELF0 + s] + (d - s * DSL);
    sCP[pos] = make_int2(d, o);
  }
  if (d == NN) dstOff[NN] = ET;
}

__global__ __launch_bounds__(256) void k_self0(int2* __restrict__ sCP, int* __restrict__ sRow,
    const int* __restrict__ meta)
{
  int n = blockIdx.x * 256 + threadIdx.x;
  if (n < NN) {
    int s = n / DSL;
    int pos = meta[O0 + SELF0 + s] + (n - s * DSL);
    sCP[pos] = make_int2(n, 0);
    sRow[pos] = n;
  }
}

__global__ __launch_bounds__(256) void k_scatter(const int* __restrict__ ei, const int* __restrict__ et,
    int* __restrict__ meta, int2* __restrict__ sCP, int* __restrict__ sRow,
    int* __restrict__ dstCursor, int doMsg)
{
  __shared__ int h[NBIN], base[NBIN], lh[NBIN];
  int tid = threadIdx.x;
  int start = blockIdx.x * 4096;
  int end = min(NE, start + 4096);
  for (int i = tid; i < NBIN; i += 256) { h[i] = 0; lh[i] = 0; }
  __syncthreads();
  for (int e = start + tid; e < end; e += 256) {
    atomicAdd(&h[et[e] * NDS + ei[e] / DSL], 1);
  }
  __syncthreads();
  for (int i = tid; i < NBIN; i += 256)
    if (h[i]) base[i] = atomicAdd(&meta[CU0 + i], h[i]);
  __syncthreads();
  for (int e = start + tid; e < end; e += 256) {
    int row = ei[e];
    int bin = et[e] * NDS + row / DSL;
    int pos = base[bin] + atomicAdd(&lh[bin], 1);
    int slot = doMsg ? atomicAdd(&dstCursor[row], 1) : 0;
    sCP[pos] = make_int2(ei[NE + e], slot);
    if (!doMsg) sRow[pos] = row;
  }
}

// per-tile metadata: binary search bin containing tile t -> {e0, nrows, rel}
__global__ __launch_bounds__(256) void k_tinfo(const int* __restrict__ meta,
    int4* __restrict__ tinfo)
{
  int t = blockIdx.x * 256 + threadIdx.x;
  if (t >= MAXTILES) return;
  int ntiles = meta[T0 + NBIN];
  if (t >= ntiles) { tinfo[t] = make_int4(0, 0, 0, 0); return; }
  int lo = 0, hi = NBIN;
  while (lo < hi) {
    int mid = (lo + hi + 1) >> 1;
    if (meta[T0 + mid] <= t) lo = mid; else hi = mid - 1;
  }
  int bin = lo;
  int e0 = meta[O0 + bin] + (t - meta[T0 + bin]) * 64;
  int nr = min(64, meta[O0 + bin] + meta[C0 + bin] - e0);
  tinfo[t] = make_int4(e0, nr, bin >> 6, 0);   // rel = bin/64 (16 = self)
}

// Tiles are (rel, dst-slice) binned: all 64 msg rows of a tile land in one
// ~2.8MB dst window -> L2-resident write-allocate, clustered writeback.
// Fast path: LDS-only barriers + 3-slot reg prefetch pipeline (R3-validated).
__global__ __launch_bounds__(256) void k_gemm(const float* __restrict__ xf,
    const unsigned short* __restrict__ xb,
    const unsigned short* __restrict__ wT, const int* __restrict__ meta,
    const int2* __restrict__ sCP, const int* __restrict__ sRow,
    const int4* __restrict__ tinfo,
    unsigned short* __restrict__ msg, float* __restrict__ out,
    int xbf, int msgmode)
{
  __shared__ short As[64 * 17 * 8];
  __shared__ short Es[64 * 136];
  __shared__ int Pos2[2][64];
  __shared__ int Rows[64];

  int tid = threadIdx.x;
  int ntiles = meta[T0 + NBIN];
  int b0 = blockIdx.x * TPB;
  if (b0 >= ntiles) return;

  int lane = tid & 63, wave = tid >> 6;
  int q = lane >> 4, l15 = lane & 15;
  int m = tid >> 2, ug = tid & 3;

  if (xbf && msgmode) {
    // slot S: staged this iter (data in regs); G: gathers issued; P: sCP in flight
    short8 pfS[4]; int cyS; bool vS; int relS, nrS;
    int2 cpG; bool vG; int relG, nrG;
    int2 cpP; bool vP; int relP, nrP;

    {   // prologue S = tile b0
      int4 ifo = tinfo[b0];
      nrS = ifo.y; relS = ifo.z;
      vS = m < nrS;
      int2 cp = sCP[vS ? (ifo.x + m) : ifo.x];
      cyS = cp.y;
      const unsigned short* xr = xb + (size_t)cp.x * 128;
      #pragma unroll
      for (int s = 0; s < 4; ++s) {
        short8 v = (short8)(short)0;
        if (vS) v = *(const short8*)(xr + (ug * 4 + s) * 8);
        pfS[s] = v;
      }
    }
    if (TPB > 1 && b0 + 1 < ntiles) {   // prologue G = tile b0+1 (sCP only)
      int4 ifo = tinfo[b0 + 1];
      nrG = ifo.y; relG = ifo.z;
      vG = m < nrG;
      cpG = sCP[vG ? (ifo.x + m) : ifo.x];
    } else { vG = false; nrG = 0; relG = relS; cpG = make_int2(0, 0); }

    int rprev = -1;
    short8 bfr[2][4];
    for (int ti = 0; ti < TPB; ++ti) {
      int lt = b0 + ti;
      if (lt >= ntiles) break;
      int curR = relS, curNr = nrS;

      // 1. stage S from regs
      #pragma unroll
      for (int s = 0; s < 4; ++s)
        *(short8*)&As[(m * 17 + ug * 4 + s) * 8] = pfS[s];
      if (ug == 0) Pos2[ti & 1][m] = vS ? cyS : 0;

      // 2. issue tinfo+sCP for tile lt+2
      if (ti + 2 < TPB && lt + 2 < ntiles) {
        int4 ifo = tinfo[lt + 2];
        nrP = ifo.y; relP = ifo.z;
        vP = m < nrP;
        cpP = sCP[vP ? (ifo.x + m) : ifo.x];
      } else { vP = false; nrP = 0; relP = relG; cpP = make_int2(0, 0); }

      // 3. issue gathers for G (in flight across barriers)
      short8 pfN[4];
      {
        const unsigned short* xr = xb + (size_t)cpG.x * 128;
        #pragma unroll
        for (int s = 0; s < 4; ++s) {
          short8 v = (short8)(short)0;
          if (vG) v = *(const short8*)(xr + (ug * 4 + s) * 8);
          pfN[s] = v;
        }
      }

      // 4. B frags (reload only on rel change; bins rel-major so rare)
      if (curR != rprev) {
        const unsigned short* wr = wT + curR * 16384;
        #pragma unroll
        for (int ns = 0; ns < 2; ++ns)
          #pragma unroll
          for (int kk = 0; kk < 4; ++kk)
            bfr[ns][kk] = *(const short8*)(wr + (wave * 32 + ns * 16 + l15) * 128 + kk * 32 + q * 8);
        rprev = curR;
      }

      lds_barrier();   // bar1: As/Pos2 visible; prior Es reads drained

      // 5. MFMA
      f32x4 acc[4][2];
      #pragma unroll
      for (int ms = 0; ms < 4; ++ms)
        #pragma unroll
        for (int ns = 0; ns < 2; ++ns)
          acc[ms][ns] = (f32x4){0.f, 0.f, 0.f, 0.f};
      #pragma unroll
      for (int kk = 0; kk < 4; ++kk) {
        short8 af[4];
        #pragma unroll
        for (int ms = 0; ms < 4; ++ms)
          af[ms] = *(const short8*)&As[((ms * 16 + l15) * 17 + kk * 4 + q) * 8];
        #pragma unroll
        for (int ms = 0; ms < 4; ++ms)
          #pragma unroll
          for (int ns = 0; ns < 2; ++ns)
            acc[ms][ns] = __builtin_amdgcn_mfma_f32_16x16x32_bf16(af[ms], bfr[ns][kk], acc[ms][ns], 0, 0, 0);
      }

      // 6. transpose to Es
      #pragma unroll
      for (int ms = 0; ms < 4; ++ms)
        #pragma unroll
        for (int ns = 0; ns < 2; ++ns)
          #pragma unroll
          for (int reg = 0; reg < 4; ++reg)
            Es[(ms * 16 + q * 4 + reg) * 136 + wave * 32 + ns * 16 + l15] =
                (short)f2bf(acc[ms][ns][reg]);

      lds_barrier();   // bar2: Es visible; MFMA As-reads drained

      // 7. full-row msg stores (nontemporal; all rows in one dst-slice window)
      #pragma unroll
      for (int i = 0; i < 4; ++i) {
        int row = wave * 16 + i * 4 + q;
        short8 v = *(const short8*)&Es[row * 136 + l15 * 8];
        if (row < curNr)
          __builtin_nontemporal_store(v,
              (short8*)(msg + (size_t)Pos2[ti & 1][row] * 128 + l15 * 8));
      }

      // 8. rotate pipeline
      #pragma unroll
      for (int s = 0; s < 4; ++s) pfS[s] = pfN[s];
      cyS = cpG.y; vS = vG; relS = relG; nrS = nrG;
      cpG = cpP;   vG = vP; relG = relP; nrG = nrP;
    }
    return;
  }

  // ---------------- generic fallback ----------------
  int rprev = -1;
  short8 bfr[2][4];
  for (int ti = 0; ti < TPB; ++ti) {
    int lt = b0 + ti;
    if (lt >= ntiles) break;
    int4 ifo = tinfo[lt];
    int e0 = ifo.x, nrows = ifo.y, rel = ifo.z;

    bool valid = m < nrows;
    int e = valid ? (e0 + m) : e0;
    int2 cp = sCP[e];
    if (ug == 0) {
      Pos2[0][m] = valid ? cp.y : 0;
      if (!msgmode) Rows[m] = valid ? sRow[e] : 0;
    }
    int c = cp.x;
    if (xbf) {
      const unsigned short* xr = xb + (size_t)c * 128;
      #pragma unroll
      for (int s = 0; s < 4; ++s) {
        int u = ug * 4 + s;
        short8 pk = (short8)(short)0;
        if (valid) pk = *(const short8*)(xr + u * 8);
        *(short8*)&As[(m * 17 + u) * 8] = pk;
      }
    } else {
      const float* xr = xf + (size_t)c * 128;
      #pragma unroll
      for (int s = 0; s < 4; ++s) {
        int u = ug * 4 + s;
        float4 f0 = make_float4(0.f, 0.f, 0.f, 0.f), f1 = f0;
        if (valid) {
          f0 = *(const float4*)(xr + u * 8);
          f1 = *(const float4*)(xr + u * 8 + 4);
        }
        short8 pk;
        pk[0] = (short)f2bf(f0.x); pk[1] = (short)f2bf(f0.y);
        pk[2] = (short)f2bf(f0.z); pk[3] = (short)f2bf(f0.w);
        pk[4] = (short)f2bf(f1.x); pk[5] = (short)f2bf(f1.y);
        pk[6] = (short)f2bf(f1.z); pk[7] = (short)f2bf(f1.w);
        *(short8*)&As[(m * 17 + u) * 8] = pk;
      }
    }
    __syncthreads();

    if (rel != rprev) {
      const unsigned short* wr = wT + rel * 16384;
      #pragma unroll
      for (int ns = 0; ns < 2; ++ns)
        #pragma unroll
        for (int kk = 0; kk < 4; ++kk)
          bfr[ns][kk] = *(const short8*)(wr + (wave * 32 + ns * 16 + l15) * 128 + kk * 32 + q * 8);
      rprev = rel;
    }

    f32x4 acc[4][2];
    #pragma unroll
    for (int ms = 0; ms < 4; ++ms)
      #pragma unroll
      for (int ns = 0; ns < 2; ++ns)
        acc[ms][ns] = (f32x4){0.f, 0.f, 0.f, 0.f};
    #pragma unroll
    for (int kk = 0; kk < 4; ++kk) {
      short8 af[4];
      #pragma unroll
      for (int ms = 0; ms < 4; ++ms)
        af[ms] = *(const short8*)&As[((ms * 16 + l15) * 17 + kk * 4 + q) * 8];
      #pragma unroll
      for (int ms = 0; ms < 4; ++ms)
        #pragma unroll
        for (int ns = 0; ns < 2; ++ns)
          acc[ms][ns] = __builtin_amdgcn_mfma_f32_16x16x32_bf16(af[ms], bfr[ns][kk], acc[ms][ns], 0, 0, 0);
    }

    if (msgmode) {
      __syncthreads();
      #pragma unroll
      for (int ms = 0; ms < 4; ++ms)
        #pragma unroll
        for (int ns = 0; ns < 2; ++ns)
          #pragma unroll
          for (int reg = 0; reg < 4; ++reg)
            Es[(ms * 16 + q * 4 + reg) * 136 + wave * 32 + ns * 16 + l15] =
                (short)f2bf(acc[ms][ns][reg]);
      __syncthreads();
      #pragma unroll
      for (int i = 0; i < 4; ++i) {
        int row = wave * 16 + i * 4 + q;
        short8 v = *(const short8*)&Es[row * 136 + l15 * 8];
        if (row < nrows)
          __builtin_nontemporal_store(v,
              (short8*)(msg + (size_t)Pos2[0][row] * 128 + l15 * 8));
      }
      __syncthreads();
    } else {
      #pragma unroll
      for (int ms = 0; ms < 4; ++ms)
        #pragma unroll
        for (int reg = 0; reg < 4; ++reg) {
          int mrow = ms * 16 + q * 4 + reg;
          if (mrow < nrows) {
            float* op = out + (size_t)Rows[mrow] * 128 + wave * 32 + l15;
            unsafeAtomicAdd(op, acc[ms][0][reg]);
            unsafeAtomicAdd(op + 16, acc[ms][1][reg]);
          }
        }
      __syncthreads();
    }
  }
}

// one 16-lane group per dst (4 dsts/wave): dwordx4 row loads, fp32 accumulate, one store
__global__ __launch_bounds__(256) void k_reduce(const unsigned short* __restrict__ msg,
    const int* __restrict__ dstOff, float* __restrict__ out)
{
  int d = blockIdx.x * 16 + (threadIdx.x >> 4);
  if (d >= NN) return;
  int sl = threadIdx.x & 15;
  int s = dstOff[d], e = dstOff[d + 1];
  const unsigned short* base = msg + (size_t)sl * 8;
  float a[8], bacc[8];
  #pragma unroll
  for (int i = 0; i < 8; ++i) { a[i] = 0.f; bacc[i] = 0.f; }
  int j = s;
  for (; j + 1 < e; j += 2) {
    u32x4 v0 = __builtin_nontemporal_load((const u32x4*)(base + (size_t)j * 128));
    u32x4 v1 = __builtin_nontemporal_load((const u32x4*)(base + (size_t)(j + 1) * 128));
    #pragma unroll
    for (int c = 0; c < 4; ++c) {
      a[2 * c]     += __builtin_bit_cast(float, v0[c] << 16);
      a[2 * c + 1] += __builtin_bit_cast(float, v0[c] & 0xffff0000u);
      bacc[2 * c]     += __builtin_bit_cast(float, v1[c] << 16);
      bacc[2 * c + 1] += __builtin_bit_cast(float, v1[c] & 0xffff0000u);
    }
  }
  if (j < e) {
    u32x4 v0 = __builtin_nontemporal_load((const u32x4*)(base + (size_t)j * 128));
    #pragma unroll
    for (int c = 0; c < 4; ++c) {
      a[2 * c]     += __builtin_bit_cast(float, v0[c] << 16);
      a[2 * c + 1] += __builtin_bit_cast(float, v0[c] & 0xffff0000u);
    }
  }
  f32x4 w0, w1;
  w0[0] = a[0] + bacc[0]; w0[1] = a[1] + bacc[1]; w0[2] = a[2] + bacc[2]; w0[3] = a[3] + bacc[3];
  w1[0] = a[4] + bacc[4]; w1[1] = a[5] + bacc[5]; w1[2] = a[6] + bacc[6]; w1[3] = a[7] + bacc[7];
  float* op = out + (size_t)d * 128 + sl * 8;
  __builtin_nontemporal_store(w0, (f32x4*)op);
  __builtin_nontemporal_store(w1, (f32x4*)(op + 4));
}

extern "C" void kernel_launch(void* const* d_in, const int* in_sizes, int n_in,
                              void* d_out, int out_size, void* d_ws, size_t ws_size,
                              hipStream_t stream)
{
  const float* x      = (const float*)d_in[0];
  const int*   ei     = (const int*)d_in[1];
  const int*   et     = (const int*)d_in[2];
  const float* bases  = (const float*)d_in[3];
  const float* coef   = (const float*)d_in[4];
  const float* w_self = (const float*)d_in[5];
  float* out = (float*)d_out;
  char* ws = (char*)d_ws;
  unsigned short* wT = (unsigned short*)(ws + WT_OFF);
  int* meta      = (int*)(ws + META_OFF);
  int* dstHist   = (int*)(ws + DH_OFF);
  int4* tinfo    = (int4*)(ws + TI_OFF);     // aliases dstHist (dead after scan1)
  int* dstOff    = (int*)(ws + DO_OFF);
  int* dstCursor = (int*)(ws + DC_OFF);
  int* blockSums = (int*)(ws + BS_OFF);
  int2* sCP      = (int2*)(ws + SCP_OFF);
  int* sRow      = (int*)(ws + SR_OFF);      // aliases xb (mode-exclusive)
  unsigned short* xb = (unsigned short*)(ws + XB_OFF);

  const int modeB = (ws_size >= NEED_B) ? 1 : 0;
  const int modeA = (modeB || ws_size >= NEED_A) ? 1 : 0;
  unsigned short* msg = (unsigned short*)(ws + (modeB ? MSGB_OFF : MSGA_OFF));

  hipMemsetAsync(ws + META_OFF, 0, 17536 + 400000, stream);  // meta + dstHist
  k_prep<<<modeB ? (WGRID + 12500) : WGRID, 256, 0, stream>>>(bases, coef, w_self, wT, x, xb);
  k_hist<<<256, 256, 0, stream>>>(ei, et, meta, dstHist);
  if (modeA) {
    k_scan1<<<SCANB, 256, 0, stream>>>(dstHist, dstOff, blockSums);
    k_scan2<<<1, 512, 0, stream>>>(blockSums, meta);
    k_scan3<<<SCANB, 256, 0, stream>>>(dstOff, blockSums, dstCursor, sCP, meta);
  } else {
    k_scan2<<<1, 512, 0, stream>>>(blockSums, meta);
    k_self0<<<SCANB, 256, 0, stream>>>(sCP, sRow, meta);
    hipMemsetAsync(d_out, 0, (size_t)NN * D * 4, stream);
  }
  k_scatter<<<(NE + 4095) / 4096, 256, 0, stream>>>(ei, et, meta, sCP, sRow, dstCursor, modeA);
  k_tinfo<<<TINFOG, 256, 0, stream>>>(meta, tinfo);
  k_gemm<<<GEMMG, 256, 0, stream>>>(x, xb, wT, meta, sCP, sRow, tinfo, msg, out, modeB, modeA);
  if (modeA)
    k_reduce<<<(NN + 15) / 16, 256, 0, stream>>>(msg, dstOff, out);
}

// Round 6
// 328.763 us; speedup vs baseline: 1.1173x; 1.1173x over previous
//
#include <hip/hip_runtime.h>

#define NN 100000
#define NE 600000
#define ET (NE + NN)
#define D 128
#define NREL 16
#define SCANB 391   // 391*256 = 100096 >= NN
#define MAXTILES 10954
#define GEMMG MAXTILES           // 1 tile per block
#define WGRID 1088  // 17*16384/256

typedef short short8 __attribute__((ext_vector_type(8)));
typedef float f32x4 __attribute__((ext_vector_type(4)));
typedef unsigned int u32x4 __attribute__((ext_vector_type(4)));

// meta layout (ints)
#define C0 0    // counts[17]
#define O0 20   // offsets[18]
#define CU0 40  // cursors[17]
#define T0 60   // tileoff[18]

// ws layout (bytes) — R2-validated
#define WT_OFF   0                 // 17*128*128 bf16 = 557056
#define META_OFF 557056            // 512
#define DH_OFF   557568            // dstHist: 100000 ints
#define DO_OFF   957568            // dstOff: 100001 ints
#define DC_OFF   1357576           // dstCursor: 100000 ints
#define BS_OFF   1757576           // blockSums: 391 ints (pad)
#define SCP_OFF  1759576           // sCP: 700064 int2
#define SR_OFF   7360088           // sRow (fallback only): 700000 ints
#define XB_OFF   10160096          // xb: 100000*128 bf16
#define MSGB_OFF 35760096          // msg (mode B)
#define MSGA_OFF 10160096          // msg (mode A, no xb)
#define NEED_B   (MSGB_OFF + (size_t)ET * 128 * 2)
#define NEED_A   (MSGA_OFF + (size_t)ET * 128 * 2)

__device__ __forceinline__ unsigned short f2bf(float f) {
  unsigned u = __builtin_bit_cast(unsigned, f);
  u += 0x7fffu + ((u >> 16) & 1u);   // RNE; inputs finite/normal
  return (unsigned short)(u >> 16);
}

// LDS-only barrier: no vmcnt drain (R3/R4/R5-validated construct)
__device__ __forceinline__ void lds_barrier() {
  asm volatile("s_waitcnt lgkmcnt(0)" ::: "memory");
  __builtin_amdgcn_s_barrier();
}

// blockIdx < WGRID: wT[r][o][i] = sum_b coef[r,b]*bases[b][i][o]; slot16 = w_self.
// else: x fp32 -> xb bf16 (4 elems/thread).
__global__ __launch_bounds__(256) void k_prep(const float* __restrict__ bases,
    const float* __restrict__ coef, const float* __restrict__ w_self,
    unsigned short* __restrict__ wT, const float* __restrict__ x,
    unsigned short* __restrict__ xb)
{
  if (blockIdx.x < WGRID) {
    int idx = blockIdx.x * 256 + threadIdx.x;   // < 17*16384
    int r = idx >> 14;
    int t = idx & 16383;
    float v;
    if (r < 16) {
      int o = t >> 7, i = t & 127;
      float acc = 0.f;
      #pragma unroll
      for (int b = 0; b < 8; ++b)
        acc += coef[r * 8 + b] * bases[b * 16384 + i * 128 + o];
      v = acc;
    } else {
      v = w_self[t];
    }
    wT[idx] = f2bf(v);
  } else {
    int i = (blockIdx.x - WGRID) * 256 + threadIdx.x;
    if (i >= NN * D / 4) return;
    f32x4 f = __builtin_nontemporal_load((const f32x4*)(x + (size_t)i * 4));
    unsigned short s0 = f2bf(f[0]), s1 = f2bf(f[1]), s2 = f2bf(f[2]), s3 = f2bf(f[3]);
    unsigned long long pk = (unsigned long long)s0 | ((unsigned long long)s1 << 16)
                          | ((unsigned long long)s2 << 32) | ((unsigned long long)s3 << 48);
    *(unsigned long long*)(xb + (size_t)i * 4) = pk;
  }
}

// rel histogram (LDS) + dst histogram (global atomics)
__global__ __launch_bounds__(256) void k_hist(const int* __restrict__ ei,
    const int* __restrict__ et, int* __restrict__ meta, int* __restrict__ dstHist)
{
  __shared__ int h[16];
  int tid = threadIdx.x;
  if (tid < 16) h[tid] = 0;
  __syncthreads();
  for (int e = blockIdx.x * 256 + tid; e < NE; e += gridDim.x * 256) {
    atomicAdd(&h[et[e]], 1);
    atomicAdd(&dstHist[ei[e]], 1);
  }
  __syncthreads();
  if (tid < 16) atomicAdd(&meta[C0 + tid], h[tid]);
}

__global__ __launch_bounds__(256) void k_scan1(const int* __restrict__ dstHist,
    int* __restrict__ dstOff, int* __restrict__ blockSums)
{
  __shared__ int sh[256];
  int tid = threadIdx.x;
  int d = blockIdx.x * 256 + tid;
  int v = (d < NN) ? (dstHist[d] + 1) : 0;   // +1: virtual self edge
  sh[tid] = v;
  __syncthreads();
  #pragma unroll
  for (int ofs = 1; ofs < 256; ofs <<= 1) {
    int t = (tid >= ofs) ? sh[tid - ofs] : 0;
    __syncthreads();
    sh[tid] += t;
    __syncthreads();
  }
  if (d < NN) dstOff[d] = sh[tid] - v;
  if (tid == 255) blockSums[blockIdx.x] = sh[tid];
}

// parallel Hillis-Steele over 512 (SCANB padded) + serial 17-bin meta on tid0
__global__ __launch_bounds__(512) void k_scan2(int* __restrict__ blockSums, int* __restrict__ meta)
{
  __shared__ int sh[512];
  int tid = threadIdx.x;
  int v = (tid < SCANB) ? blockSums[tid] : 0;
  sh[tid] = v;
  __syncthreads();
  #pragma unroll
  for (int ofs = 1; ofs < 512; ofs <<= 1) {
    int t = (tid >= ofs) ? sh[tid - ofs] : 0;
    __syncthreads();
    sh[tid] += t;
    __syncthreads();
  }
  if (tid == 0) {
    meta[C0 + 16] = NN;
    int off = 0, toff = 0;
    for (int r = 0; r <= 16; ++r) {
      meta[O0 + r] = off;
      meta[CU0 + r] = off;
      meta[T0 + r] = toff;
      int c = meta[C0 + r];
      off += c;
      toff += (c + 63) >> 6;
    }
    meta[O0 + 17] = off;
    meta[T0 + 17] = toff;
  }
  if (tid < SCANB) blockSums[tid] = sh[tid] - v;   // exclusive prefix
}

__global__ __launch_bounds__(256) void k_scan3(int* __restrict__ dstOff,
    const int* __restrict__ blockSums, int* __restrict__ dstCursor,
    int2* __restrict__ sCP)
{
  int tid = threadIdx.x;
  int d = blockIdx.x * 256 + tid;
  int base = blockSums[blockIdx.x];
  if (d < NN) {
    int o = dstOff[d] + base;
    dstOff[d] = o;
    dstCursor[d] = o + 1;
    sCP[NE + d] = make_int2(d, o);
  }
  if (d == NN) dstOff[NN] = ET;
}

__global__ __launch_bounds__(256) void k_self0(int2* __restrict__ sCP, int* __restrict__ sRow)
{
  int n = blockIdx.x * 256 + threadIdx.x;
  if (n < NN) { sCP[NE + n] = make_int2(n, 0); sRow[NE + n] = n; }
}

__global__ __launch_bounds__(256) void k_scatter(const int* __restrict__ ei, const int* __restrict__ et,
    int* __restrict__ meta, int2* __restrict__ sCP, int* __restrict__ sRow,
    int* __restrict__ dstCursor, int doMsg)
{
  __shared__ int h[16], base[16], lh[16];
  int tid = threadIdx.x;
  int start = blockIdx.x * 4096;
  int end = min(NE, start + 4096);
  if (tid < 16) { h[tid] = 0; lh[tid] = 0; }
  __syncthreads();
  for (int e = start + tid; e < end; e += 256)
    atomicAdd(&h[et[e]], 1);
  __syncthreads();
  if (tid < 16) base[tid] = atomicAdd(&meta[CU0 + tid], h[tid]);
  __syncthreads();
  for (int e = start + tid; e < end; e += 256) {
    int r = et[e];
    int row = ei[e];
    int pos = base[r] + atomicAdd(&lh[r], 1);
    int slot = doMsg ? atomicAdd(&dstCursor[row], 1) : 0;
    sCP[pos] = make_int2(ei[NE + e], slot);
    if (!doMsg) sRow[pos] = row;
  }
}

// ONE tile per block: gather -> As -> barrier -> MFMA -> direct epilogue.
// No Es transpose, no second barrier, LDS ~18KB (more resident blocks).
// msgmode: bf16 stores straight from acc (4 rows x 32B per instr; L2 merges).
// !msgmode: fp32 atomic adds to out.
__global__ __launch_bounds__(256) void k_gemm(const float* __restrict__ xf,
    const unsigned short* __restrict__ xb,
    const unsigned short* __restrict__ wT, const int* __restrict__ meta,
    const int2* __restrict__ sCP, const int* __restrict__ sRow,
    unsigned short* __restrict__ msg, float* __restrict__ out,
    int xbf, int msgmode)
{
  __shared__ short As[64 * 17 * 8];   // 17.4KB staging
  __shared__ int Pos[64];
  __shared__ int Rows[64];
  __shared__ int Ms[80];

  int tid = threadIdx.x;
  if (tid < 80) Ms[tid] = meta[tid];
  __syncthreads();
  int ntiles = Ms[T0 + 17];
  int b = blockIdx.x;
  if (b >= ntiles) return;

  int lane = tid & 63, wave = tid >> 6;
  int q = lane >> 4, l15 = lane & 15;
  int m = tid >> 2, ug = tid & 3;

  int r = 0;
  while (r < 16 && Ms[T0 + r + 1] <= b) ++r;
  int boff = Ms[O0 + r];
  int e0 = boff + (b - Ms[T0 + r]) * 64;
  int nr = min(64, boff + Ms[C0 + r] - e0);

  bool valid = m < nr;
  int e = valid ? (e0 + m) : e0;
  int2 cp = sCP[e];
  if (ug == 0) {
    Pos[m] = valid ? cp.y : 0;
    if (!msgmode) Rows[m] = valid ? sRow[e] : 0;
  }

  // ---- stage gather row m into As ----
  if (xbf) {
    const unsigned short* xr = xb + (size_t)cp.x * 128;
    #pragma unroll
    for (int s = 0; s < 4; ++s) {
      int u = ug * 4 + s;
      short8 pk = (short8)(short)0;
      if (valid) pk = *(const short8*)(xr + u * 8);
      *(short8*)&As[(m * 17 + u) * 8] = pk;
    }
  } else {
    const float* xr = xf + (size_t)cp.x * 128;
    #pragma unroll
    for (int s = 0; s < 4; ++s) {
      int u = ug * 4 + s;
      float4 f0 = make_float4(0.f, 0.f, 0.f, 0.f), f1 = f0;
      if (valid) {
        f0 = *(const float4*)(xr + u * 8);
        f1 = *(const float4*)(xr + u * 8 + 4);
      }
      short8 pk;
      pk[0] = (short)f2bf(f0.x); pk[1] = (short)f2bf(f0.y);
      pk[2] = (short)f2bf(f0.z); pk[3] = (short)f2bf(f0.w);
      pk[4] = (short)f2bf(f1.x); pk[5] = (short)f2bf(f1.y);
      pk[6] = (short)f2bf(f1.z); pk[7] = (short)f2bf(f1.w);
      *(short8*)&As[(m * 17 + u) * 8] = pk;
    }
  }

  // ---- B frags (pre-barrier; overlaps other waves' staging) ----
  short8 bfr[2][4];
  {
    const unsigned short* wr = wT + r * 16384;
    #pragma unroll
    for (int ns = 0; ns < 2; ++ns)
      #pragma unroll
      for (int kk = 0; kk < 4; ++kk)
        bfr[ns][kk] = *(const short8*)(wr + (wave * 32 + ns * 16 + l15) * 128 + kk * 32 + q * 8);
  }

  lds_barrier();   // As/Pos/Rows visible

  // ---- MFMA ----
  f32x4 acc[4][2];
  #pragma unroll
  for (int ms = 0; ms < 4; ++ms)
    #pragma unroll
    for (int ns = 0; ns < 2; ++ns)
      acc[ms][ns] = (f32x4){0.f, 0.f, 0.f, 0.f};
  #pragma unroll
  for (int kk = 0; kk < 4; ++kk) {
    short8 af[4];
    #pragma unroll
    for (int ms = 0; ms < 4; ++ms)
      af[ms] = *(const short8*)&As[((ms * 16 + l15) * 17 + kk * 4 + q) * 8];
    #pragma unroll
    for (int ms = 0; ms < 4; ++ms)
      #pragma unroll
      for (int ns = 0; ns < 2; ++ns)
        acc[ms][ns] = __builtin_amdgcn_mfma_f32_16x16x32_bf16(af[ms], bfr[ns][kk], acc[ms][ns], 0, 0, 0);
  }

  // ---- epilogue ----
  if (msgmode) {
    #pragma unroll
    for (int ms = 0; ms < 4; ++ms)
      #pragma unroll
      for (int reg = 0; reg < 4; ++reg) {
        int erow = ms * 16 + q * 4 + reg;
        if (erow < nr) {
          unsigned short* mp = msg + (size_t)Pos[erow] * 128 + wave * 32 + l15;
          mp[0]  = f2bf(acc[ms][0][reg]);
          mp[16] = f2bf(acc[ms][1][reg]);
        }
      }
  } else {
    #pragma unroll
    for (int ms = 0; ms < 4; ++ms)
      #pragma unroll
      for (int reg = 0; reg < 4; ++reg) {
        int erow = ms * 16 + q * 4 + reg;
        if (erow < nr) {
          float* op = out + (size_t)Rows[erow] * 128 + wave * 32 + l15;
          unsafeAtomicAdd(op, acc[ms][0][reg]);
          unsafeAtomicAdd(op + 16, acc[ms][1][reg]);
        }
      }
  }
}

// one 16-lane group per dst (4 dsts/wave): dwordx4 row loads, fp32 accumulate, one store
__global__ __launch_bounds__(256) void k_reduce(const unsigned short* __restrict__ msg,
    const int* __restrict__ dstOff, float* __restrict__ out)
{
  int d = blockIdx.x * 16 + (threadIdx.x >> 4);
  if (d >= NN) return;
  int sl = threadIdx.x & 15;
  int s = dstOff[d], e = dstOff[d + 1];
  const unsigned short* base = msg + (size_t)sl * 8;
  float a[8], bacc[8];
  #pragma unroll
  for (int i = 0; i < 8; ++i) { a[i] = 0.f; bacc[i] = 0.f; }
  int j = s;
  for (; j + 1 < e; j += 2) {
    u32x4 v0 = __builtin_nontemporal_load((const u32x4*)(base + (size_t)j * 128));
    u32x4 v1 = __builtin_nontemporal_load((const u32x4*)(base + (size_t)(j + 1) * 128));
    #pragma unroll
    for (int c = 0; c < 4; ++c) {
      a[2 * c]     += __builtin_bit_cast(float, v0[c] << 16);
      a[2 * c + 1] += __builtin_bit_cast(float, v0[c] & 0xffff0000u);
      bacc[2 * c]     += __builtin_bit_cast(float, v1[c] << 16);
      bacc[2 * c + 1] += __builtin_bit_cast(float, v1[c] & 0xffff0000u);
    }
  }
  if (j < e) {
    u32x4 v0 = __builtin_nontemporal_load((const u32x4*)(base + (size_t)j * 128));
    #pragma unroll
    for (int c = 0; c < 4; ++c) {
      a[2 * c]     += __builtin_bit_cast(float, v0[c] << 16);
      a[2 * c + 1] += __builtin_bit_cast(float, v0[c] & 0xffff0000u);
    }
  }
  f32x4 w0, w1;
  w0[0] = a[0] + bacc[0]; w0[1] = a[1] + bacc[1]; w0[2] = a[2] + bacc[2]; w0[3] = a[3] + bacc[3];
  w1[0] = a[4] + bacc[4]; w1[1] = a[5] + bacc[5]; w1[2] = a[6] + bacc[6]; w1[3] = a[7] + bacc[7];
  float* op = out + (size_t)d * 128 + sl * 8;
  __builtin_nontemporal_store(w0, (f32x4*)op);
  __builtin_nontemporal_store(w1, (f32x4*)(op + 4));
}

extern "C" void kernel_launch(void* const* d_in, const int* in_sizes, int n_in,
                              void* d_out, int out_size, void* d_ws, size_t ws_size,
                              hipStream_t stream)
{
  const float* x      = (const float*)d_in[0];
  const int*   ei     = (const int*)d_in[1];
  const int*   et     = (const int*)d_in[2];
  const float* bases  = (const float*)d_in[3];
  const float* coef   = (const float*)d_in[4];
  const float* w_self = (const float*)d_in[5];
  float* out = (float*)d_out;
  char* ws = (char*)d_ws;
  unsigned short* wT = (unsigned short*)(ws + WT_OFF);
  int* meta      = (int*)(ws + META_OFF);
  int* dstHist   = (int*)(ws + DH_OFF);
  int* dstOff    = (int*)(ws + DO_OFF);
  int* dstCursor = (int*)(ws + DC_OFF);
  int* blockSums = (int*)(ws + BS_OFF);
  int2* sCP      = (int2*)(ws + SCP_OFF);
  int* sRow      = (int*)(ws + SR_OFF);
  unsigned short* xb = (unsigned short*)(ws + XB_OFF);

  const int modeB = (ws_size >= NEED_B) ? 1 : 0;
  const int modeA = (modeB || ws_size >= NEED_A) ? 1 : 0;
  unsigned short* msg = (unsigned short*)(ws + (modeB ? MSGB_OFF : MSGA_OFF));

  hipMemsetAsync(ws + META_OFF, 0, 512 + 400000, stream);  // meta + dstHist
  k_prep<<<modeB ? (WGRID + 12500) : WGRID, 256, 0, stream>>>(bases, coef, w_self, wT, x, xb);
  k_hist<<<256, 256, 0, stream>>>(ei, et, meta, dstHist);
  if (modeA) {
    k_scan1<<<SCANB, 256, 0, stream>>>(dstHist, dstOff, blockSums);
    k_scan2<<<1, 512, 0, stream>>>(blockSums, meta);
    k_scan3<<<SCANB, 256, 0, stream>>>(dstOff, blockSums, dstCursor, sCP);
  } else {
    k_scan2<<<1, 512, 0, stream>>>(blockSums, meta);
    k_self0<<<SCANB, 256, 0, stream>>>(sCP, sRow);
    hipMemsetAsync(d_out, 0, (size_t)NN * D * 4, stream);
  }
  k_scatter<<<(NE + 4095) / 4096, 256, 0, stream>>>(ei, et, meta, sCP, sRow, dstCursor, modeA);
  k_gemm<<<GEMMG, 256, 0, stream>>>(x, xb, wT, meta, sCP, sRow, msg, out, modeB, modeA);
  if (modeA)
    k_reduce<<<(NN + 15) / 16, 256, 0, stream>>>(msg, dstOff, out);
}